// Round 12
// baseline (886.852 us; speedup 1.0000x reference)
//
#include <hip/hip_runtime.h>
#include <stdint.h>
#include <math.h>

#define NV 32768      // N = B*T
#define DIM 256       // D
#define KCB 1024      // K
#define NSAMP 5       // S

typedef double f64x4 __attribute__((ext_vector_type(4)));

// ---------------- threefry2x32 (20 rounds), JAX key = (0, 42) ----------------
__device__ __forceinline__ uint32_t rotl32(uint32_t v, int r) {
  return __builtin_rotateleft32(v, (uint32_t)r);   // force v_alignbit_b32
}

__device__ __forceinline__ void threefry2x32(uint32_t c0, uint32_t c1,
                                             uint32_t& o0, uint32_t& o1) {
  const uint32_t k0 = 0u, k1 = 42u;
  const uint32_t k2 = k0 ^ k1 ^ 0x1BD11BDAu;
  uint32_t x0 = c0 + k0, x1 = c1 + k1;
  x0 += x1; x1 = rotl32(x1, 13); x1 ^= x0;
  x0 += x1; x1 = rotl32(x1, 15); x1 ^= x0;
  x0 += x1; x1 = rotl32(x1, 26); x1 ^= x0;
  x0 += x1; x1 = rotl32(x1,  6); x1 ^= x0;
  x0 += k1; x1 += k2 + 1u;
  x0 += x1; x1 = rotl32(x1, 17); x1 ^= x0;
  x0 += x1; x1 = rotl32(x1, 29); x1 ^= x0;
  x0 += x1; x1 = rotl32(x1, 16); x1 ^= x0;
  x0 += x1; x1 = rotl32(x1, 24); x1 ^= x0;
  x0 += k2; x1 += k0 + 2u;
  x0 += x1; x1 = rotl32(x1, 13); x1 ^= x0;
  x0 += x1; x1 = rotl32(x1, 15); x1 ^= x0;
  x0 += x1; x1 = rotl32(x1, 26); x1 ^= x0;
  x0 += x1; x1 = rotl32(x1,  6); x1 ^= x0;
  x0 += k0; x1 += k1 + 3u;
  x0 += x1; x1 = rotl32(x1, 17); x1 ^= x0;
  x0 += x1; x1 = rotl32(x1, 29); x1 ^= x0;
  x0 += x1; x1 = rotl32(x1, 16); x1 ^= x0;
  x0 += x1; x1 = rotl32(x1, 24); x1 ^= x0;
  x0 += k1; x1 += k2 + 4u;
  x0 += x1; x1 = rotl32(x1, 13); x1 ^= x0;
  x0 += x1; x1 = rotl32(x1, 15); x1 ^= x0;
  x0 += x1; x1 = rotl32(x1, 26); x1 ^= x0;
  x0 += x1; x1 = rotl32(x1,  6); x1 ^= x0;
  x0 += k2; x1 += k0 + 5u;
  o0 = x0; o1 = x1;
}

// exact path: f32(-log(x)) via f64 log (rel err < 2^-44) — bit-compatible with
// the correctly-rounded reference logf (validated R1-R11).
__device__ __forceinline__ float neg_log_f32(float xf) {
  uint32_t i = __float_as_uint(xf);
  int e = ((int)(i - 0x3f3504f3u)) >> 23;
  double m = (double)__uint_as_float(i - (uint32_t)(e << 23));
  double z = (m - 1.0) / (m + 1.0);
  double p = z * z;
  double poly = 0x1.1111111111111p-4;          // 1/15
  poly = fma(poly, p, 0x1.3b13b13b13b14p-4);   // 1/13
  poly = fma(poly, p, 0x1.745d1745d1746p-4);   // 1/11
  poly = fma(poly, p, 0x1.c71c71c71c71cp-4);   // 1/9
  poly = fma(poly, p, 0x1.2492492492492p-3);   // 1/7
  poly = fma(poly, p, 0x1.999999999999ap-3);   // 1/5
  poly = fma(poly, p, 0x1.5555555555555p-2);   // 1/3
  poly = fma(poly, p, 1.0);
  double r = fma(-2.0 * z, poly, (double)(-e) * 0x1.62e42fefa39efp-1);
  return (float)r;
}

__device__ __forceinline__ float u_from_bits(uint32_t bits) {
  uint32_t m = bits >> 9;
  return (m == 0u) ? 1.17549435e-38f
                   : (__uint_as_float(m | 0x3f800000u) - 1.0f);
}

__device__ __forceinline__ float gumbel_exact(uint32_t bits) {
  float u = u_from_bits(bits);
  float t = neg_log_f32(u);
  return neg_log_f32(t);
}

// screening approximation (fused fallback): 1-ulp v_log_f32
__device__ __forceinline__ float gumbel_approx(uint32_t bits) {
  float u = u_from_bits(bits);
  float t = __log2f(u) * (-0.6931471805599453f);
  return __log2f(t) * (-0.6931471805599453f);
}

#define E2G 4e-5f   // near-tie window (>> 2x approx error, ~13x margin)

// ------------------------------- prep kernels --------------------------------

// f64 transpose: wT64[d*1024 + k] = (double)emb[k*256 + d], tiled via LDS
__global__ __launch_bounds__(256) void k_prep64(const float* __restrict__ emb,
                                                double* __restrict__ wT64) {
  __shared__ float tile[64][65];
  int bk = blockIdx.x;
  int bd = blockIdx.y;
  int t = threadIdx.x;
  int tr = t >> 6, tc = t & 63;
#pragma unroll
  for (int i = 0; i < 16; ++i) {
    int kk = tr + i * 4;
    tile[kk][tc] = emb[(size_t)(bk * 64 + kk) * 256 + bd * 64 + tc];
  }
  __syncthreads();
#pragma unroll
  for (int i = 0; i < 16; ++i) {
    int dd = tr + i * 4;
    wT64[(size_t)(bd * 64 + dd) * 1024 + bk * 64 + tc] = (double)tile[tc][dd];
  }
}

// sequential f32 sum of squares per row (mimic XLA:CPU minor-axis reduce)
__global__ __launch_bounds__(256) void k_rowsumsq(const float* __restrict__ a,
                                                  float* __restrict__ outp,
                                                  int rows) {
  int r = blockIdx.x * blockDim.x + threadIdx.x;
  if (r >= rows) return;
  const float* p = a + (size_t)r * DIM;
  float acc = 0.0f;
  for (int i = 0; i < DIM; ++i) {
    float pi = p[i];
    acc = __fadd_rn(acc, __fmul_rn(pi, pi));
  }
  outp[r] = acc;
}

// ----------------------- split path: GEMM then sampler -----------------------

// 32 rows/block, all 1024 cols: f64 MFMA logits -> global buffer (local rows).
// 4 column-tiles concurrently (C0..C3) share one `a` per step -> 4 independent
// MFMA chains/wave (validated R11: MFMA-floor-bound). Bit-identical chains.
__global__ __launch_bounds__(256) void k_logits(const float* __restrict__ x,
                                                const double* __restrict__ wT64,
                                                const float* __restrict__ wsum,
                                                float* __restrict__ logits,
                                                int chunkbase) {
  __shared__ float xl[32 * 260];
  __shared__ float xs[32];
  int nb = blockIdx.x;
  int t = threadIdx.x;
  int lane = t & 63, wv = t >> 6;
  int m = lane & 15, g = lane >> 4;
  int rg = wv >> 1, chf = wv & 1;   // row-half, col-half

#pragma unroll
  for (int i = 0; i < 32; ++i)
    xl[i * 260 + t] = x[((size_t)(chunkbase + nb * 32) + i) * 256 + t];
  __syncthreads();

  if (t < 32) {
    const float* p = xl + t * 260;
    float acc = 0.0f;
    for (int i = 0; i < DIM; ++i) {
      float pi = p[i];
      acc = __fadd_rn(acc, __fmul_rn(pi, pi));
    }
    xs[t] = acc;
  }
  __syncthreads();

  const float* ap = xl + (rg * 16 + m) * 260 + g;
  for (int ch = 0; ch < 4; ++ch) {
#pragma unroll 1
    for (int cq = 0; cq < 2; ++cq) {          // quad of 16-col tiles
      int kgb = ch * 256 + chf * 128 + cq * 64 + m;   // tile i at +i*16
      f64x4 C0 = {0.0, 0.0, 0.0, 0.0};
      f64x4 C1 = {0.0, 0.0, 0.0, 0.0};
      f64x4 C2 = {0.0, 0.0, 0.0, 0.0};
      f64x4 C3 = {0.0, 0.0, 0.0, 0.0};
      const double* bp = wT64 + (size_t)g * 1024 + kgb;  // d = 4*step + g
#pragma unroll 4
      for (int step = 0; step < 64; ++step) {
        double a = (double)ap[step * 4];
        const double* bs = bp + (size_t)step * 4096;
        double b0 = bs[0];
        double b1 = bs[16];
        double b2 = bs[32];
        double b3 = bs[48];
        C0 = __builtin_amdgcn_mfma_f64_16x16x4f64(a, b0, C0, 0, 0, 0);
        C1 = __builtin_amdgcn_mfma_f64_16x16x4f64(a, b1, C1, 0, 0, 0);
        C2 = __builtin_amdgcn_mfma_f64_16x16x4f64(a, b2, C2, 0, 0, 0);
        C3 = __builtin_amdgcn_mfma_f64_16x16x4f64(a, b3, C3, 0, 0, 0);
      }
      f64x4 Cs[4] = {C0, C1, C2, C3};
#pragma unroll
      for (int i = 0; i < 4; ++i) {
        int kglob = kgb + i * 16;
        float ws_k = wsum[kglob];
#pragma unroll
        for (int j = 0; j < 4; ++j) {
          int rloc = rg * 16 + g * 4 + j;
          float l32 = __fsub_rn(__fmul_rn(2.0f, (float)Cs[i][j]),
                                __fadd_rn(ws_k, xs[rloc]));
          logits[(size_t)(nb * 32 + rloc) * 1024 + kglob] = l32;
        }
      }
    }
  }
}

// sampler v5: thread = (row, k-sixteenth p), ONE sample (s = blockIdx.y).
// 5-reg state instead of 25; grid 5x larger (full occupancy). Enumeration,
// winner/runner policy and exact resolution identical to validated R8-R11.
__global__ __launch_bounds__(256) void k_sampler(const float* __restrict__ logits,
                                                 int* __restrict__ samples,
                                                 int* __restrict__ cnt,
                                                 int chunkbase) {
  int t = threadIdx.x;
  int p = t & 15;
  int rloc = blockIdx.x * 16 + (t >> 4);
  int s = blockIdx.y;
  int row = chunkbase + rloc;
  uint32_t sbase = (uint32_t)s * 33554432u + (uint32_t)row * 1024u;

  const float4* lp = (const float4*)(logits + (size_t)rloc * 1024) + p;

  float    wvt = -INFINITY;
  int      wk = 0, rk = 0;
  uint32_t wbits = 0u, rbits = 0u;
  int      rflag = 0;

#pragma unroll 2
  for (int j = 0; j < 16; ++j) {
    float4 f = lp[(size_t)j * 16];
    float lvs[4] = {f.x, f.y, f.z, f.w};
    int kb = 4 * p + 64 * j;
#pragma unroll
    for (int e = 0; e < 4; ++e) {
      int k = kb + e;
      float lv = lvs[e];
      uint32_t o0, o1;
      threefry2x32(0u, sbase + (uint32_t)k, o0, o1);
      uint32_t bits = o0 ^ o1;
      // m==0 -> u=0 -> g=-inf: never wins (winners ~ +8.5); inf/NaN-safe.
      float u = __uint_as_float((bits >> 9) | 0x3f800000u) - 1.0f;
      float tt = __log2f(u) * (-0.6931471805599453f);
      float g  = __log2f(tt) * (-0.6931471805599453f);
      float vt = __fadd_rn(g, lv);
      float d = vt - wvt;
      if (fabsf(d) < E2G) {                    // rare near-tie (either side)
        bool up = vt > wvt;
        rk    = up ? wk    : k;
        rbits = up ? wbits : bits;
        rflag = 1;
      }
      bool gt = vt > wvt;                      // strict >, k ascending
      wvt   = gt ? vt   : wvt;
      wk    = gt ? k    : wk;
      wbits = gt ? bits : wbits;
    }
  }

  // exact resolution (refetch logits — bit-identical values) + 16-lane reduce
  const float* lrow_p = logits + (size_t)rloc * 1024;
  float ev = __fadd_rn(gumbel_exact(wbits), lrow_p[wk]);
  int ek = wk;
  if (rflag) {
    float er = __fadd_rn(gumbel_exact(rbits), lrow_p[rk]);
    if (er > ev || (er == ev && rk < ek)) { ev = er; ek = rk; }
  }
#pragma unroll
  for (int off = 1; off < 16; off <<= 1) {
    float v2 = __shfl_xor(ev, off, 64);
    int   k2 = __shfl_xor(ek, off, 64);
    if (v2 > ev || (v2 == ev && k2 < ek)) { ev = v2; ek = k2; }
  }
  if (p == 0) {
    samples[s * NV + row] = ek;
    atomicAdd(&cnt[ek], 1);
  }
}

// --------------------- fused fallback (R4, validated) ------------------------
__global__ __launch_bounds__(256) void k_fused(const float* __restrict__ x,
                                               const double* __restrict__ wT64,
                                               const float* __restrict__ wsum,
                                               const float* __restrict__ xsum,
                                               int* __restrict__ samples,
                                               int* __restrict__ cnt) {
  __shared__ float xl[16 * 260];
  __shared__ float ll[256 * 17];
  __shared__ float xs[16];
  __shared__ float vred[4 * 16 * 5];
  __shared__ int   kred[4 * 16 * 5];

  int nb = blockIdx.x;
  int t = threadIdx.x;
  int lane = t & 63, wv = t >> 6;
  int m = lane & 15, g = lane >> 4;
  int r = t & 15, kg = t >> 4;

#pragma unroll
  for (int i = 0; i < 16; ++i)
    xl[i * 260 + t] = x[((size_t)nb * 16 + i) * 256 + t];
  if (t < 16) xs[t] = xsum[nb * 16 + t];
  __syncthreads();

  float    wvt[NSAMP], wlv[NSAMP], rlv[NSAMP];
  int      wk[NSAMP], rk[NSAMP];
  uint32_t wbits[NSAMP], rbits[NSAMP];
  uint32_t rvmask = 0;
#pragma unroll
  for (int s = 0; s < NSAMP; ++s) {
    wvt[s] = -INFINITY; wlv[s] = 0.f; wk[s] = 0; wbits[s] = 0u;
    rlv[s] = 0.f; rk[s] = 0; rbits[s] = 0u;
  }
  uint32_t rowbase = ((uint32_t)nb * 16u + (uint32_t)r) * 1024u;

  for (int ch = 0; ch < 4; ++ch) {
    for (int ct = 0; ct < 4; ++ct) {
      int klocal = wv * 64 + ct * 16 + m;
      int kglob = ch * 256 + klocal;
      f64x4 C = {0.0, 0.0, 0.0, 0.0};
      const double* bp = wT64 + (size_t)g * 1024 + kglob;
      const float* ap = xl + m * 260 + g;
#pragma unroll 8
      for (int step = 0; step < 64; ++step) {
        double a = (double)ap[step * 4];
        double b = bp[(size_t)step * 4096];
        C = __builtin_amdgcn_mfma_f64_16x16x4f64(a, b, C, 0, 0, 0);
      }
      float ws_k = wsum[kglob];
#pragma unroll
      for (int j = 0; j < 4; ++j) {
        int row = g * 4 + j;
        float l32 = __fsub_rn(__fmul_rn(2.0f, (float)C[j]),
                              __fadd_rn(ws_k, xs[row]));
        ll[klocal * 17 + row] = l32;
      }
    }
    __syncthreads();
#pragma unroll 1
    for (int i = 0; i < 16; ++i) {
      int kl = kg + (i << 4);
      float lv = ll[kl * 17 + r];
      int gki = (ch << 8) + kl;
      uint32_t cbase = rowbase + (uint32_t)gki;
#pragma unroll
      for (int s = 0; s < NSAMP; ++s) {
        uint32_t o0, o1;
        threefry2x32(0u, cbase + (uint32_t)s * 33554432u, o0, o1);
        uint32_t bits = o0 ^ o1;
        float vt = __fadd_rn(gumbel_approx(bits), lv);
        if (vt > wvt[s]) {
          if (wvt[s] > vt - E2G) {
            rk[s] = wk[s]; rbits[s] = wbits[s]; rlv[s] = wlv[s];
            rvmask |= (1u << s);
          }
          wvt[s] = vt; wk[s] = gki; wbits[s] = bits; wlv[s] = lv;
        } else if (vt > wvt[s] - E2G) {
          rk[s] = gki; rbits[s] = bits; rlv[s] = lv;
          rvmask |= (1u << s);
        }
      }
    }
    __syncthreads();
  }

#pragma unroll
  for (int s = 0; s < NSAMP; ++s) {
    float ev = __fadd_rn(gumbel_exact(wbits[s]), wlv[s]);
    int ek = wk[s];
    if (rvmask & (1u << s)) {
      float er = __fadd_rn(gumbel_exact(rbits[s]), rlv[s]);
      if (er > ev || (er == ev && rk[s] < ek)) { ev = er; ek = rk[s]; }
    }
#pragma unroll
    for (int off = 16; off <= 32; off <<= 1) {
      float v2 = __shfl_xor(ev, off, 64);
      int   k2 = __shfl_xor(ek, off, 64);
      if (v2 > ev || (v2 == ev && k2 < ek)) { ev = v2; ek = k2; }
    }
    if (g == 0) {
      vred[(wv * 16 + r) * 5 + s] = ev;
      kred[(wv * 16 + r) * 5 + s] = ek;
    }
  }
  __syncthreads();
  if (t < 80) {
    int rr = t / 5, s = t % 5;
    float best = vred[rr * 5 + s];
    int bk2 = kred[rr * 5 + s];
#pragma unroll
    for (int w = 1; w < 4; ++w) {
      float v2 = vred[(w * 16 + rr) * 5 + s];
      int   k2 = kred[(w * 16 + rr) * 5 + s];
      if (v2 > best || (v2 == best && k2 < bk2)) { best = v2; bk2 = k2; }
    }
    int n = nb * 16 + rr;
    samples[s * NV + n] = bk2;
    atomicAdd(&cnt[bk2], 1);
  }
}

// ------------------------------ tail kernels ---------------------------------

__global__ __launch_bounds__(1024) void k_meta(const float* __restrict__ ema_count,
                                               const int* __restrict__ cnt,
                                               int* __restrict__ offs,
                                               int* __restrict__ cursor,
                                               double* __restrict__ ncn64,
                                               float* __restrict__ out_count,
                                               float* __restrict__ out_perp) {
  __shared__ int sc[1024];
  __shared__ double red[1024];
  int k = threadIdx.x;
  int v = cnt[k];
  sc[k] = v;
  __syncthreads();
  for (int off = 1; off < 1024; off <<= 1) {
    int a = (k >= off) ? sc[k - off] : 0;
    __syncthreads();
    sc[k] += a;
    __syncthreads();
  }
  int excl = sc[k] - v;
  offs[k] = excl;
  cursor[k] = excl;

  double ec = (double)v * 0.2;
  double nc0 = 0.999 * (double)ema_count[k] + 0.001 * ec;
  red[k] = nc0;
  __syncthreads();
  for (int off = 512; off > 0; off >>= 1) {
    if (k < off) red[k] += red[k + off];
    __syncthreads();
  }
  double ntot = red[0];
  __syncthreads();
  double ncn = (nc0 + 1e-5) / (ntot + (double)KCB * 1e-5) * ntot;
  ncn64[k] = ncn;
  out_count[k] = (float)ncn;

  double avg = ec / (double)NV;
  red[k] = avg * log(avg + 1e-10);
  __syncthreads();
  for (int off = 512; off > 0; off >>= 1) {
    if (k < off) red[k] += red[k + off];
    __syncthreads();
  }
  if (k == 0) out_perp[0] = (float)exp(-red[0]);
}

__global__ __launch_bounds__(256) void k_fill(const int* __restrict__ samples,
                                              int* __restrict__ cursor,
                                              uint32_t* __restrict__ list) {
  int idx = blockIdx.x * 256 + threadIdx.x;   // < 163840
  int k = samples[idx];
  int n = idx & (NV - 1);
  int pos = atomicAdd(&cursor[k], 1);
  list[pos] = (uint32_t)n;
}

__global__ __launch_bounds__(256) void k_weight2(const float* __restrict__ x,
                                                 const float* __restrict__ ema_w,
                                                 const uint32_t* __restrict__ list,
                                                 const int* __restrict__ offs,
                                                 const int* __restrict__ cnt,
                                                 const double* __restrict__ ncn64,
                                                 float* __restrict__ out_w,
                                                 float* __restrict__ out_emb,
                                                 float* __restrict__ emb32) {
  int k = blockIdx.x, d = threadIdx.x;
  const uint32_t* lp = list + offs[k];
  int mcnt = cnt[k];
  double acc0 = 0.0, acc1 = 0.0;
  int i = 0;
  for (; i + 2 <= mcnt; i += 2) {
    uint32_t n0 = lp[i], n1 = lp[i + 1];
    acc0 += (double)x[(size_t)n0 * 256 + d];
    acc1 += (double)x[(size_t)n1 * 256 + d];
  }
  if (i < mcnt) acc0 += (double)x[(size_t)lp[i] * 256 + d];
  double dw = 0.2 * (acc0 + acc1);
  double nw = 0.999 * (double)ema_w[(size_t)k * 256 + d] + 0.001 * dw;
  float nw32 = (float)nw;
  float e = __fdiv_rn(nw32, (float)ncn64[k]);
  size_t i2 = (size_t)k * 256 + d;
  out_w[i2] = nw32;
  out_emb[i2] = e;
  emb32[i2] = e;
}

__global__ __launch_bounds__(256) void k_quant(const float* __restrict__ x,
                                               const int* __restrict__ samples,
                                               const float* __restrict__ emb32,
                                               float* __restrict__ out_q,
                                               double* __restrict__ lossacc) {
  __shared__ int s5[16][5];
  __shared__ double wred[4];
  int bid = blockIdx.x;
  int t = threadIdx.x;
  if (t < 80) {
    int rr = t / 5, s = t % 5;
    s5[rr][s] = samples[s * NV + bid * 16 + rr];
  }
  __syncthreads();
  double lacc = 0.0;
#pragma unroll 1
  for (int rr = 0; rr < 16; ++rr) {
    size_t n = (size_t)bid * 16 + rr;
    float xv = x[n * DIM + t];
    float acc = emb32[(size_t)s5[rr][0] * DIM + t];
#pragma unroll
    for (int s = 1; s < NSAMP; ++s)
      acc = __fadd_rn(acc, emb32[(size_t)s5[rr][s] * DIM + t]);
    float q = __fdiv_rn(acc, 5.0f);
    out_q[n * DIM + t] = __fadd_rn(xv, __fsub_rn(q, xv));
    float df = __fsub_rn(xv, q);
    lacc += (double)df * (double)df;
  }
  for (int off = 32; off > 0; off >>= 1) lacc += __shfl_down(lacc, off, 64);
  int wid = t >> 6, lane = t & 63;
  if (lane == 0) wred[wid] = lacc;
  __syncthreads();
  if (t == 0) {
    double b = wred[0] + wred[1] + wred[2] + wred[3];
    __hip_atomic_fetch_add(lossacc, b, __ATOMIC_RELAXED, __HIP_MEMORY_SCOPE_AGENT);
  }
}

__global__ void k_loss(const double* __restrict__ lossacc,
                       float* __restrict__ out_loss) {
  out_loss[0] = (float)(0.25 * (lossacc[0] / (double)(NV * DIM)));
}

// ------------------------------- launcher ------------------------------------
extern "C" void kernel_launch(void* const* d_in, const int* in_sizes, int n_in,
                              void* d_out, int out_size, void* d_ws, size_t ws_size,
                              hipStream_t stream) {
  const float* x     = (const float*)d_in[0];   // [64,512,256]
  const float* emb   = (const float*)d_in[1];   // [1024,256]
  const float* ema_c = (const float*)d_in[2];   // [1024]
  const float* ema_w = (const float*)d_in[3];   // [1024,256]

  float* out      = (float*)d_out;
  float* out_q    = out;                 // 8,388,608
  float* out_loss = out + 8388608;       // 1
  float* out_perp = out + 8388609;       // 1
  float* out_emb  = out + 8388610;       // 262,144
  float* out_cnt  = out + 8650754;       // 1,024
  float* out_w    = out + 8651778;       // 262,144

  char* ws = (char*)d_ws;

  // unified layout (shared by split + fallback paths)
  double*   wT64    = (double*)(ws + 0);          // 2,097,152
  float*    wsum    = (float*)(ws + 2097152);     // 4,096
  float*    xsum    = (float*)(ws + 2101248);     // 131,072 (fallback only)
  int*      samples = (int*)(ws + 2232320);       // 655,360
  int*      cnt     = (int*)(ws + 2887680);       // 4,096  [zeroed]
  double*   lossacc = (double*)(ws + 2891776);    // 8      [zeroed]
  double*   ncn64   = (double*)(ws + 2891784);    // 8,192
  int*      offs    = (int*)(ws + 2899976);       // 4,096
  int*      cursor  = (int*)(ws + 2904072);       // 4,096
  uint32_t* list    = (uint32_t*)(ws + 2908168);  // 655,360
  float*    emb32   = (float*)(ws + 3563528);     // 1,048,576
  const size_t LB   = 4612352;                    // logits base (256-aligned)
  float*    logits  = (float*)(ws + LB);          // 4096 B/row

  size_t avail = (ws_size > LB) ? (ws_size - LB) : 0;
  size_t maxr = (avail / 4096) & ~(size_t)31;
  int chunk_rows = (maxr > (size_t)NV) ? NV : (int)maxr;
  bool split = (chunk_rows >= 8192);

  hipMemsetAsync(ws + 2887680, 0, 4096 + 8, stream);
  k_prep64<<<dim3(16, 4), 256, 0, stream>>>(emb, wT64);
  k_rowsumsq<<<KCB / 256, 256, 0, stream>>>(emb, wsum, KCB);

  if (split) {
    for (int base = 0; base < NV; base += chunk_rows) {
      int rows = (NV - base < chunk_rows) ? (NV - base) : chunk_rows;
      k_logits<<<rows / 32, 256, 0, stream>>>(x, wT64, wsum, logits, base);
      k_sampler<<<dim3(rows / 16, 5), 256, 0, stream>>>(logits, samples, cnt, base);
    }
  } else {
    k_rowsumsq<<<NV / 256, 256, 0, stream>>>(x, xsum, NV);
    k_fused<<<NV / 16, 256, 0, stream>>>(x, wT64, wsum, xsum, samples, cnt);
  }

  k_meta<<<1, 1024, 0, stream>>>(ema_c, cnt, offs, cursor, ncn64,
                                 out_cnt, out_perp);
  k_fill<<<NV * NSAMP / 256, 256, 0, stream>>>(samples, cursor, list);
  k_weight2<<<KCB, 256, 0, stream>>>(x, ema_w, list, offs, cnt, ncn64,
                                     out_w, out_emb, emb32);
  k_quant<<<NV / 16, 256, 0, stream>>>(x, samples, emb32, out_q, lossacc);
  k_loss<<<1, 1, 0, stream>>>(lossacc, out_loss);
}

// Round 13
// 780.967 us; speedup vs baseline: 1.1356x; 1.1356x over previous
//
#include <hip/hip_runtime.h>
#include <stdint.h>
#include <math.h>

#define NV 32768      // N = B*T
#define DIM 256       // D
#define KCB 1024      // K
#define NSAMP 5       // S

typedef double f64x4 __attribute__((ext_vector_type(4)));

// ---------------- threefry2x32 (20 rounds), JAX key = (0, 42) ----------------
__device__ __forceinline__ uint32_t rotl32(uint32_t v, int r) {
  return __builtin_rotateleft32(v, (uint32_t)r);   // v_alignbit_b32
}

__device__ __forceinline__ void threefry2x32(uint32_t c0, uint32_t c1,
                                             uint32_t& o0, uint32_t& o1) {
  const uint32_t k0 = 0u, k1 = 42u;
  const uint32_t k2 = k0 ^ k1 ^ 0x1BD11BDAu;
  uint32_t x0 = c0 + k0, x1 = c1 + k1;
  x0 += x1; x1 = rotl32(x1, 13); x1 ^= x0;
  x0 += x1; x1 = rotl32(x1, 15); x1 ^= x0;
  x0 += x1; x1 = rotl32(x1, 26); x1 ^= x0;
  x0 += x1; x1 = rotl32(x1,  6); x1 ^= x0;
  x0 += k1; x1 += k2 + 1u;
  x0 += x1; x1 = rotl32(x1, 17); x1 ^= x0;
  x0 += x1; x1 = rotl32(x1, 29); x1 ^= x0;
  x0 += x1; x1 = rotl32(x1, 16); x1 ^= x0;
  x0 += x1; x1 = rotl32(x1, 24); x1 ^= x0;
  x0 += k2; x1 += k0 + 2u;
  x0 += x1; x1 = rotl32(x1, 13); x1 ^= x0;
  x0 += x1; x1 = rotl32(x1, 15); x1 ^= x0;
  x0 += x1; x1 = rotl32(x1, 26); x1 ^= x0;
  x0 += x1; x1 = rotl32(x1,  6); x1 ^= x0;
  x0 += k0; x1 += k1 + 3u;
  x0 += x1; x1 = rotl32(x1, 17); x1 ^= x0;
  x0 += x1; x1 = rotl32(x1, 29); x1 ^= x0;
  x0 += x1; x1 = rotl32(x1, 16); x1 ^= x0;
  x0 += x1; x1 = rotl32(x1, 24); x1 ^= x0;
  x0 += k1; x1 += k2 + 4u;
  x0 += x1; x1 = rotl32(x1, 13); x1 ^= x0;
  x0 += x1; x1 = rotl32(x1, 15); x1 ^= x0;
  x0 += x1; x1 = rotl32(x1, 26); x1 ^= x0;
  x0 += x1; x1 = rotl32(x1,  6); x1 ^= x0;
  x0 += k2; x1 += k0 + 5u;
  o0 = x0; o1 = x1;
}

// exact path: f32(-log(x)) via f64 log (rel err < 2^-44) — bit-compatible with
// the correctly-rounded reference logf (validated R1-R12).
__device__ __forceinline__ float neg_log_f32(float xf) {
  uint32_t i = __float_as_uint(xf);
  int e = ((int)(i - 0x3f3504f3u)) >> 23;
  double m = (double)__uint_as_float(i - (uint32_t)(e << 23));
  double z = (m - 1.0) / (m + 1.0);
  double p = z * z;
  double poly = 0x1.1111111111111p-4;          // 1/15
  poly = fma(poly, p, 0x1.3b13b13b13b14p-4);   // 1/13
  poly = fma(poly, p, 0x1.745d1745d1746p-4);   // 1/11
  poly = fma(poly, p, 0x1.c71c71c71c71cp-4);   // 1/9
  poly = fma(poly, p, 0x1.2492492492492p-3);   // 1/7
  poly = fma(poly, p, 0x1.999999999999ap-3);   // 1/5
  poly = fma(poly, p, 0x1.5555555555555p-2);   // 1/3
  poly = fma(poly, p, 1.0);
  double r = fma(-2.0 * z, poly, (double)(-e) * 0x1.62e42fefa39efp-1);
  return (float)r;
}

__device__ __forceinline__ float u_from_bits(uint32_t bits) {
  uint32_t m = bits >> 9;
  return (m == 0u) ? 1.17549435e-38f
                   : (__uint_as_float(m | 0x3f800000u) - 1.0f);
}

__device__ __forceinline__ float gumbel_exact(uint32_t bits) {
  float u = u_from_bits(bits);
  float t = neg_log_f32(u);
  return neg_log_f32(t);
}

// screening approximation (fused fallback): 1-ulp v_log_f32
__device__ __forceinline__ float gumbel_approx(uint32_t bits) {
  float u = u_from_bits(bits);
  float t = __log2f(u) * (-0.6931471805599453f);
  return __log2f(t) * (-0.6931471805599453f);
}

#define E2G 4e-5f   // near-tie window (>> 2x approx error, ~13x margin)

// ------------------------------- prep kernel ---------------------------------

// merged: f64 transpose (blocks 0..63) + emb row-sumsq (blocks 64..67, exact
// sequential f32 order) + cnt/lossacc zeroing (block 64).
__global__ __launch_bounds__(256) void k_prep_all(const float* __restrict__ emb,
                                                  double* __restrict__ wT64,
                                                  float* __restrict__ wsum,
                                                  int* __restrict__ cnt,
                                                  double* __restrict__ lossacc) {
  int b = blockIdx.x;
  int t = threadIdx.x;
  if (b < 64) {
    __shared__ float tile[64][65];
    int bk = b & 15;          // k-tile 0..15
    int bd = b >> 4;          // d-tile 0..3
    int tr = t >> 6, tc = t & 63;
#pragma unroll
    for (int i = 0; i < 16; ++i) {
      int kk = tr + i * 4;
      tile[kk][tc] = emb[(size_t)(bk * 64 + kk) * 256 + bd * 64 + tc];
    }
    __syncthreads();
#pragma unroll
    for (int i = 0; i < 16; ++i) {
      int dd = tr + i * 4;
      wT64[(size_t)(bd * 64 + dd) * 1024 + bk * 64 + tc] = (double)tile[tc][dd];
    }
  } else {
    int r = (b - 64) * 256 + t;     // 1024 rows
    const float* p = emb + (size_t)r * DIM;
    float acc = 0.0f;
    for (int i = 0; i < DIM; ++i) {
      float pi = p[i];
      acc = __fadd_rn(acc, __fmul_rn(pi, pi));
    }
    wsum[r] = acc;
    if (b == 64) {
      cnt[t] = 0; cnt[t + 256] = 0; cnt[t + 512] = 0; cnt[t + 768] = 0;
      if (t == 0) lossacc[0] = 0.0;
    }
  }
}

// sequential f32 sum of squares per row (fallback path)
__global__ __launch_bounds__(256) void k_rowsumsq(const float* __restrict__ a,
                                                  float* __restrict__ outp,
                                                  int rows) {
  int r = blockIdx.x * blockDim.x + threadIdx.x;
  if (r >= rows) return;
  const float* p = a + (size_t)r * DIM;
  float acc = 0.0f;
  for (int i = 0; i < DIM; ++i) {
    float pi = p[i];
    acc = __fadd_rn(acc, __fmul_rn(pi, pi));
  }
  outp[r] = acc;
}

// ----------------------- split path: GEMM then sampler -----------------------

// 32 rows/block, all 1024 cols: f64 MFMA logits -> global buffer (local rows).
// 4 column-tiles concurrently (C0..C3) share one `a` per step -> 4 independent
// MFMA chains/wave (validated R11: MFMA-floor-bound). Bit-identical chains.
__global__ __launch_bounds__(256) void k_logits(const float* __restrict__ x,
                                                const double* __restrict__ wT64,
                                                const float* __restrict__ wsum,
                                                float* __restrict__ logits,
                                                int chunkbase) {
  __shared__ float xl[32 * 260];
  __shared__ float xs[32];
  int nb = blockIdx.x;
  int t = threadIdx.x;
  int lane = t & 63, wv = t >> 6;
  int m = lane & 15, g = lane >> 4;
  int rg = wv >> 1, chf = wv & 1;   // row-half, col-half

#pragma unroll
  for (int i = 0; i < 32; ++i)
    xl[i * 260 + t] = x[((size_t)(chunkbase + nb * 32) + i) * 256 + t];
  __syncthreads();

  if (t < 32) {
    const float* p = xl + t * 260;
    float acc = 0.0f;
    for (int i = 0; i < DIM; ++i) {
      float pi = p[i];
      acc = __fadd_rn(acc, __fmul_rn(pi, pi));
    }
    xs[t] = acc;
  }
  __syncthreads();

  const float* ap = xl + (rg * 16 + m) * 260 + g;
  for (int ch = 0; ch < 4; ++ch) {
#pragma unroll 1
    for (int cq = 0; cq < 2; ++cq) {          // quad of 16-col tiles
      int kgb = ch * 256 + chf * 128 + cq * 64 + m;   // tile i at +i*16
      f64x4 C0 = {0.0, 0.0, 0.0, 0.0};
      f64x4 C1 = {0.0, 0.0, 0.0, 0.0};
      f64x4 C2 = {0.0, 0.0, 0.0, 0.0};
      f64x4 C3 = {0.0, 0.0, 0.0, 0.0};
      const double* bp = wT64 + (size_t)g * 1024 + kgb;  // d = 4*step + g
#pragma unroll 4
      for (int step = 0; step < 64; ++step) {
        double a = (double)ap[step * 4];
        const double* bs = bp + (size_t)step * 4096;
        double b0 = bs[0];
        double b1 = bs[16];
        double b2 = bs[32];
        double b3 = bs[48];
        C0 = __builtin_amdgcn_mfma_f64_16x16x4f64(a, b0, C0, 0, 0, 0);
        C1 = __builtin_amdgcn_mfma_f64_16x16x4f64(a, b1, C1, 0, 0, 0);
        C2 = __builtin_amdgcn_mfma_f64_16x16x4f64(a, b2, C2, 0, 0, 0);
        C3 = __builtin_amdgcn_mfma_f64_16x16x4f64(a, b3, C3, 0, 0, 0);
      }
      f64x4 Cs[4] = {C0, C1, C2, C3};
#pragma unroll
      for (int i = 0; i < 4; ++i) {
        int kglob = kgb + i * 16;
        float ws_k = wsum[kglob];
#pragma unroll
        for (int j = 0; j < 4; ++j) {
          int rloc = rg * 16 + g * 4 + j;
          float l32 = __fsub_rn(__fmul_rn(2.0f, (float)Cs[i][j]),
                                __fadd_rn(ws_k, xs[rloc]));
          logits[(size_t)(nb * 32 + rloc) * 1024 + kglob] = l32;
        }
      }
    }
  }
}

// sampler (validated R11 structure): thread = (row, k-sixteenth p), ALL 5
// samples/thread (amortizes logit loads + loop bookkeeping — R12 showed the
// kernel is issue-bound, so amortization wins over occupancy). Branchless
// winner update; rare exec-masked near-tie runner; exact f64 resolution.
__global__ __launch_bounds__(256) void k_sampler(const float* __restrict__ logits,
                                                 int* __restrict__ samples,
                                                 int* __restrict__ cnt,
                                                 int chunkbase) {
  int t = threadIdx.x;
  int p = t & 15;
  int rloc = blockIdx.x * 16 + (t >> 4);
  int row = chunkbase + rloc;
  uint32_t rowk = (uint32_t)row * 1024u;

  const float4* lp = (const float4*)(logits + (size_t)rloc * 1024) + p;

  float    wvt[NSAMP];
  int      wk[NSAMP], rk[NSAMP];
  uint32_t wbits[NSAMP], rbits[NSAMP];
  uint32_t rmask = 0;
#pragma unroll
  for (int s = 0; s < NSAMP; ++s) {
    wvt[s] = -INFINITY; wk[s] = 0; wbits[s] = 0u; rk[s] = 0; rbits[s] = 0u;
  }

#pragma unroll 2
  for (int j = 0; j < 16; ++j) {
    float4 f = lp[(size_t)j * 16];
    float lvs[4] = {f.x, f.y, f.z, f.w};
    int kb = 4 * p + 64 * j;
#pragma unroll
    for (int e = 0; e < 4; ++e) {
      int k = kb + e;
      float lv = lvs[e];
      uint32_t cbase = rowk + (uint32_t)k;
#pragma unroll
      for (int s = 0; s < NSAMP; ++s) {
        uint32_t o0, o1;
        threefry2x32(0u, cbase + (uint32_t)s * 33554432u, o0, o1);
        uint32_t bits = o0 ^ o1;
        // m==0 -> u=0 -> g=-inf: never wins (winners ~ +8.5); inf/NaN-safe.
        float u = __uint_as_float((bits >> 9) | 0x3f800000u) - 1.0f;
        float tt = __log2f(u) * (-0.6931471805599453f);
        float g  = __log2f(tt) * (-0.6931471805599453f);
        float vt = __fadd_rn(g, lv);
        float wpre = wvt[s];
        float d = vt - wpre;
        if (fabsf(d) < E2G) {                    // rare near-tie (either side)
          bool up = d > 0.0f;
          rk[s]    = up ? wk[s]    : k;
          rbits[s] = up ? wbits[s] : bits;
          rmask |= (1u << s);
        }
        bool gt = d > 0.0f;                      // strict >, k ascending
        wvt[s]   = fmaxf(vt, wpre);
        wk[s]    = gt ? k    : wk[s];
        wbits[s] = gt ? bits : wbits[s];
      }
    }
  }

  // exact resolution (refetch logits — bit-identical values) + 16-lane reduce
  const float* lrow_p = logits + (size_t)rloc * 1024;
#pragma unroll
  for (int s = 0; s < NSAMP; ++s) {
    float ev = __fadd_rn(gumbel_exact(wbits[s]), lrow_p[wk[s]]);
    int ek = wk[s];
    if (rmask & (1u << s)) {
      float er = __fadd_rn(gumbel_exact(rbits[s]), lrow_p[rk[s]]);
      if (er > ev || (er == ev && rk[s] < ek)) { ev = er; ek = rk[s]; }
    }
#pragma unroll
    for (int off = 1; off < 16; off <<= 1) {
      float v2 = __shfl_xor(ev, off, 64);
      int   k2 = __shfl_xor(ek, off, 64);
      if (v2 > ev || (v2 == ev && k2 < ek)) { ev = v2; ek = k2; }
    }
    if (p == 0) {
      samples[s * NV + row] = ek;
      atomicAdd(&cnt[ek], 1);
    }
  }
}

// --------------------- fused fallback (R4, validated) ------------------------
__global__ __launch_bounds__(256) void k_fused(const float* __restrict__ x,
                                               const double* __restrict__ wT64,
                                               const float* __restrict__ wsum,
                                               const float* __restrict__ xsum,
                                               int* __restrict__ samples,
                                               int* __restrict__ cnt) {
  __shared__ float xl[16 * 260];
  __shared__ float ll[256 * 17];
  __shared__ float xs[16];
  __shared__ float vred[4 * 16 * 5];
  __shared__ int   kred[4 * 16 * 5];

  int nb = blockIdx.x;
  int t = threadIdx.x;
  int lane = t & 63, wv = t >> 6;
  int m = lane & 15, g = lane >> 4;
  int r = t & 15, kg = t >> 4;

#pragma unroll
  for (int i = 0; i < 16; ++i)
    xl[i * 260 + t] = x[((size_t)nb * 16 + i) * 256 + t];
  if (t < 16) xs[t] = xsum[nb * 16 + t];
  __syncthreads();

  float    wvt[NSAMP], wlv[NSAMP], rlv[NSAMP];
  int      wk[NSAMP], rk[NSAMP];
  uint32_t wbits[NSAMP], rbits[NSAMP];
  uint32_t rvmask = 0;
#pragma unroll
  for (int s = 0; s < NSAMP; ++s) {
    wvt[s] = -INFINITY; wlv[s] = 0.f; wk[s] = 0; wbits[s] = 0u;
    rlv[s] = 0.f; rk[s] = 0; rbits[s] = 0u;
  }
  uint32_t rowbase = ((uint32_t)nb * 16u + (uint32_t)r) * 1024u;

  for (int ch = 0; ch < 4; ++ch) {
    for (int ct = 0; ct < 4; ++ct) {
      int klocal = wv * 64 + ct * 16 + m;
      int kglob = ch * 256 + klocal;
      f64x4 C = {0.0, 0.0, 0.0, 0.0};
      const double* bp = wT64 + (size_t)g * 1024 + kglob;
      const float* ap = xl + m * 260 + g;
#pragma unroll 8
      for (int step = 0; step < 64; ++step) {
        double a = (double)ap[step * 4];
        double b = bp[(size_t)step * 4096];
        C = __builtin_amdgcn_mfma_f64_16x16x4f64(a, b, C, 0, 0, 0);
      }
      float ws_k = wsum[kglob];
#pragma unroll
      for (int j = 0; j < 4; ++j) {
        int row = g * 4 + j;
        float l32 = __fsub_rn(__fmul_rn(2.0f, (float)C[j]),
                              __fadd_rn(ws_k, xs[row]));
        ll[klocal * 17 + row] = l32;
      }
    }
    __syncthreads();
#pragma unroll 1
    for (int i = 0; i < 16; ++i) {
      int kl = kg + (i << 4);
      float lv = ll[kl * 17 + r];
      int gki = (ch << 8) + kl;
      uint32_t cbase = rowbase + (uint32_t)gki;
#pragma unroll
      for (int s = 0; s < NSAMP; ++s) {
        uint32_t o0, o1;
        threefry2x32(0u, cbase + (uint32_t)s * 33554432u, o0, o1);
        uint32_t bits = o0 ^ o1;
        float vt = __fadd_rn(gumbel_approx(bits), lv);
        if (vt > wvt[s]) {
          if (wvt[s] > vt - E2G) {
            rk[s] = wk[s]; rbits[s] = wbits[s]; rlv[s] = wlv[s];
            rvmask |= (1u << s);
          }
          wvt[s] = vt; wk[s] = gki; wbits[s] = bits; wlv[s] = lv;
        } else if (vt > wvt[s] - E2G) {
          rk[s] = gki; rbits[s] = bits; rlv[s] = lv;
          rvmask |= (1u << s);
        }
      }
    }
    __syncthreads();
  }

#pragma unroll
  for (int s = 0; s < NSAMP; ++s) {
    float ev = __fadd_rn(gumbel_exact(wbits[s]), wlv[s]);
    int ek = wk[s];
    if (rvmask & (1u << s)) {
      float er = __fadd_rn(gumbel_exact(rbits[s]), rlv[s]);
      if (er > ev || (er == ev && rk[s] < ek)) { ev = er; ek = rk[s]; }
    }
#pragma unroll
    for (int off = 16; off <= 32; off <<= 1) {
      float v2 = __shfl_xor(ev, off, 64);
      int   k2 = __shfl_xor(ek, off, 64);
      if (v2 > ev || (v2 == ev && k2 < ek)) { ev = v2; ek = k2; }
    }
    if (g == 0) {
      vred[(wv * 16 + r) * 5 + s] = ev;
      kred[(wv * 16 + r) * 5 + s] = ek;
    }
  }
  __syncthreads();
  if (t < 80) {
    int rr = t / 5, s = t % 5;
    float best = vred[rr * 5 + s];
    int bk2 = kred[rr * 5 + s];
#pragma unroll
    for (int w = 1; w < 4; ++w) {
      float v2 = vred[(w * 16 + rr) * 5 + s];
      int   k2 = kred[(w * 16 + rr) * 5 + s];
      if (v2 > best || (v2 == best && k2 < bk2)) { best = v2; bk2 = k2; }
    }
    int n = nb * 16 + rr;
    samples[s * NV + n] = bk2;
    atomicAdd(&cnt[bk2], 1);
  }
}

// ------------------------------ tail kernels ---------------------------------

__global__ __launch_bounds__(1024) void k_meta(const float* __restrict__ ema_count,
                                               const int* __restrict__ cnt,
                                               int* __restrict__ offs,
                                               int* __restrict__ cursor,
                                               double* __restrict__ ncn64,
                                               float* __restrict__ out_count,
                                               float* __restrict__ out_perp) {
  __shared__ int sc[1024];
  __shared__ double red[1024];
  int k = threadIdx.x;
  int v = cnt[k];
  sc[k] = v;
  __syncthreads();
  for (int off = 1; off < 1024; off <<= 1) {
    int a = (k >= off) ? sc[k - off] : 0;
    __syncthreads();
    sc[k] += a;
    __syncthreads();
  }
  int excl = sc[k] - v;
  offs[k] = excl;
  cursor[k] = excl;

  double ec = (double)v * 0.2;
  double nc0 = 0.999 * (double)ema_count[k] + 0.001 * ec;
  red[k] = nc0;
  __syncthreads();
  for (int off = 512; off > 0; off >>= 1) {
    if (k < off) red[k] += red[k + off];
    __syncthreads();
  }
  double ntot = red[0];
  __syncthreads();
  double ncn = (nc0 + 1e-5) / (ntot + (double)KCB * 1e-5) * ntot;
  ncn64[k] = ncn;
  out_count[k] = (float)ncn;

  double avg = ec / (double)NV;
  red[k] = avg * log(avg + 1e-10);
  __syncthreads();
  for (int off = 512; off > 0; off >>= 1) {
    if (k < off) red[k] += red[k + off];
    __syncthreads();
  }
  if (k == 0) out_perp[0] = (float)exp(-red[0]);
}

__global__ __launch_bounds__(256) void k_fill(const int* __restrict__ samples,
                                              int* __restrict__ cursor,
                                              uint32_t* __restrict__ list) {
  int idx = blockIdx.x * 256 + threadIdx.x;   // < 163840
  int k = samples[idx];
  int n = idx & (NV - 1);
  int pos = atomicAdd(&cursor[k], 1);
  list[pos] = (uint32_t)n;
}

__global__ __launch_bounds__(256) void k_weight2(const float* __restrict__ x,
                                                 const float* __restrict__ ema_w,
                                                 const uint32_t* __restrict__ list,
                                                 const int* __restrict__ offs,
                                                 const int* __restrict__ cnt,
                                                 const double* __restrict__ ncn64,
                                                 float* __restrict__ out_w,
                                                 float* __restrict__ out_emb,
                                                 float* __restrict__ emb32) {
  int k = blockIdx.x, d = threadIdx.x;
  const uint32_t* lp = list + offs[k];
  int mcnt = cnt[k];
  double acc0 = 0.0, acc1 = 0.0;
  int i = 0;
  for (; i + 2 <= mcnt; i += 2) {
    uint32_t n0 = lp[i], n1 = lp[i + 1];
    acc0 += (double)x[(size_t)n0 * 256 + d];
    acc1 += (double)x[(size_t)n1 * 256 + d];
  }
  if (i < mcnt) acc0 += (double)x[(size_t)lp[i] * 256 + d];
  double dw = 0.2 * (acc0 + acc1);
  double nw = 0.999 * (double)ema_w[(size_t)k * 256 + d] + 0.001 * dw;
  float nw32 = (float)nw;
  float e = __fdiv_rn(nw32, (float)ncn64[k]);
  size_t i2 = (size_t)k * 256 + d;
  out_w[i2] = nw32;
  out_emb[i2] = e;
  emb32[i2] = e;
}

__global__ __launch_bounds__(256) void k_quant(const float* __restrict__ x,
                                               const int* __restrict__ samples,
                                               const float* __restrict__ emb32,
                                               float* __restrict__ out_q,
                                               double* __restrict__ lossacc) {
  __shared__ int s5[16][5];
  __shared__ double wred[4];
  int bid = blockIdx.x;
  int t = threadIdx.x;
  if (t < 80) {
    int rr = t / 5, s = t % 5;
    s5[rr][s] = samples[s * NV + bid * 16 + rr];
  }
  __syncthreads();
  double lacc = 0.0;
#pragma unroll 1
  for (int rr = 0; rr < 16; ++rr) {
    size_t n = (size_t)bid * 16 + rr;
    float xv = x[n * DIM + t];
    float acc = emb32[(size_t)s5[rr][0] * DIM + t];
#pragma unroll
    for (int s = 1; s < NSAMP; ++s)
      acc = __fadd_rn(acc, emb32[(size_t)s5[rr][s] * DIM + t]);
    float q = __fdiv_rn(acc, 5.0f);
    out_q[n * DIM + t] = __fadd_rn(xv, __fsub_rn(q, xv));
    float df = __fsub_rn(xv, q);
    lacc += (double)df * (double)df;
  }
  for (int off = 32; off > 0; off >>= 1) lacc += __shfl_down(lacc, off, 64);
  int wid = t >> 6, lane = t & 63;
  if (lane == 0) wred[wid] = lacc;
  __syncthreads();
  if (t == 0) {
    double b = wred[0] + wred[1] + wred[2] + wred[3];
    __hip_atomic_fetch_add(lossacc, b, __ATOMIC_RELAXED, __HIP_MEMORY_SCOPE_AGENT);
  }
}

__global__ void k_loss(const double* __restrict__ lossacc,
                       float* __restrict__ out_loss) {
  out_loss[0] = (float)(0.25 * (lossacc[0] / (double)(NV * DIM)));
}

// ------------------------------- launcher ------------------------------------
extern "C" void kernel_launch(void* const* d_in, const int* in_sizes, int n_in,
                              void* d_out, int out_size, void* d_ws, size_t ws_size,
                              hipStream_t stream) {
  const float* x     = (const float*)d_in[0];   // [64,512,256]
  const float* emb   = (const float*)d_in[1];   // [1024,256]
  const float* ema_c = (const float*)d_in[2];   // [1024]
  const float* ema_w = (const float*)d_in[3];   // [1024,256]

  float* out      = (float*)d_out;
  float* out_q    = out;                 // 8,388,608
  float* out_loss = out + 8388608;       // 1
  float* out_perp = out + 8388609;       // 1
  float* out_emb  = out + 8388610;       // 262,144
  float* out_cnt  = out + 8650754;       // 1,024
  float* out_w    = out + 8651778;       // 262,144

  char* ws = (char*)d_ws;

  // unified layout (shared by split + fallback paths)
  double*   wT64    = (double*)(ws + 0);          // 2,097,152
  float*    wsum    = (float*)(ws + 2097152);     // 4,096
  float*    xsum    = (float*)(ws + 2101248);     // 131,072 (fallback only)
  int*      samples = (int*)(ws + 2232320);       // 655,360
  int*      cnt     = (int*)(ws + 2887680);       // 4,096  [zeroed in k_prep_all]
  double*   lossacc = (double*)(ws + 2891776);    // 8      [zeroed in k_prep_all]
  double*   ncn64   = (double*)(ws + 2891784);    // 8,192
  int*      offs    = (int*)(ws + 2899976);       // 4,096
  int*      cursor  = (int*)(ws + 2904072);       // 4,096
  uint32_t* list    = (uint32_t*)(ws + 2908168);  // 655,360
  float*    emb32   = (float*)(ws + 3563528);     // 1,048,576
  const size_t LB   = 4612352;                    // logits base (256-aligned)
  float*    logits  = (float*)(ws + LB);          // 4096 B/row

  size_t avail = (ws_size > LB) ? (ws_size - LB) : 0;
  size_t maxr = (avail / 4096) & ~(size_t)31;
  int chunk_rows = (maxr > (size_t)NV) ? NV : (int)maxr;
  bool split = (chunk_rows >= 8192);

  k_prep_all<<<68, 256, 0, stream>>>(emb, wT64, wsum, cnt, lossacc);

  if (split) {
    for (int base = 0; base < NV; base += chunk_rows) {
      int rows = (NV - base < chunk_rows) ? (NV - base) : chunk_rows;
      k_logits<<<rows / 32, 256, 0, stream>>>(x, wT64, wsum, logits, base);
      k_sampler<<<rows / 16, 256, 0, stream>>>(logits, samples, cnt, base);
    }
  } else {
    k_rowsumsq<<<NV / 256, 256, 0, stream>>>(x, xsum, NV);
    k_fused<<<NV / 16, 256, 0, stream>>>(x, wT64, wsum, xsum, samples, cnt);
  }

  k_meta<<<1, 1024, 0, stream>>>(ema_c, cnt, offs, cursor, ncn64,
                                 out_cnt, out_perp);
  k_fill<<<NV * NSAMP / 256, 256, 0, stream>>>(samples, cursor, list);
  k_weight2<<<KCB, 256, 0, stream>>>(x, ema_w, list, offs, cnt, ncn64,
                                     out_w, out_emb, emb32);
  k_quant<<<NV / 16, 256, 0, stream>>>(x, samples, emb32, out_q, lossacc);
  k_loss<<<1, 1, 0, stream>>>(lossacc, out_loss);
}